// Round 7
// baseline (162.748 us; speedup 1.0000x reference)
//
#include <hip/hip_runtime.h>

// RNNAdder round 7: barrier-free wave-independent recurrence, projection
// folded onto the SAME A-fragments as the recurrence (no second LDS read,
// proj off the critical path).
// B=4096, T=128, HID=64, VOCAB=10. 256 WGs x 128 thr = 512 waves; each wave
// owns M=8 sequences and ALL 64 hidden cols -> no cross-wave data flow, no
// __syncthreads in the t-loop (same-wave LDS ordering is HW-guaranteed).
// Per step t: Ak = h(t-1) A-frags (4x ds_read_b128, masked l5<8);
//   proj: logits(t-1) = Ak @ Wd (2x2 MFMA) + bd  [skipped at t=0; h(127)
//         projected after the loop]
//   rec:  x = Ak @ Whh as 4 INDEPENDENT MFMAs (latency L not 2L) + PP[cmb];
//         h(t) = tanh(x) -> 8 b16 LDS writes.
// PPT transposed [n][cmb] stride 101 (conflict-free); Hh row stride 72 halves.

typedef _Float16 half8 __attribute__((ext_vector_type(8)));
typedef float floatx16 __attribute__((ext_vector_type(16)));

#define MFMA32(A, B, C) __builtin_amdgcn_mfma_f32_32x32x16_f16((A), (B), (C), 0, 0, 0)

__global__ __launch_bounds__(128)
void rnn_mfma7(const int* __restrict__ num1, const int* __restrict__ num2,
               const float* __restrict__ E, const float* __restrict__ Wxh,
               const float* __restrict__ Whh, const float* __restrict__ bias,
               const float* __restrict__ Wd, const float* __restrict__ bd,
               float* __restrict__ out)
{
    __shared__ float P1[640], P2[640];
    __shared__ float PPT[64 * 101 + 3];                  // [n][cmb], stride 101
    __shared__ __align__(16) _Float16 Hh[2][8][72];      // per-wave h, stride 72
    __shared__ __align__(4) unsigned char cmbB[2][1024]; // per-wave cmb [t][m]

    const int tid  = threadIdx.x;
    const int w    = tid >> 6;       // wave in WG (fully independent)
    const int lane = tid & 63;
    const int l5   = lane & 31;
    const int h32  = lane >> 5;
    const int g    = blockIdx.x;
    const int s0   = g * 16 + w * 8; // first sequence of this wave

    // ---- stage 1: P1 (bias folded) / P2 ----
    for (int idx = tid; idx < 640; idx += 128) {
        int v = idx >> 6, j = idx & 63;
        float a = bias[j], b2 = 0.f;
        #pragma unroll
        for (int i = 0; i < 32; ++i) {
            float e = E[v * 32 + i];
            a  = fmaf(e, Wxh[i * 64 + j], a);
            b2 = fmaf(e, Wxh[(32 + i) * 64 + j], b2);
        }
        P1[idx] = a; P2[idx] = b2;
    }
    __syncthreads();

    // ---- stage 2: transposed PP table; zero h; stage cmb bytes ----
    for (int idx = tid; idx < 6400; idx += 128) {
        int n = idx & 63, cv = idx >> 6;
        PPT[n * 101 + cv] = P1[(cv / 10) * 64 + n] + P2[(cv % 10) * 64 + n];
    }
    {
        int* hz = (int*)&Hh[0][0][0];
        for (int i = tid; i < 576; i += 128) hz[i] = 0;
    }
    for (int idx = tid; idx < 2048; idx += 128) {
        int ww = idx >> 10, r = idx & 1023, t = r >> 3, m = r & 7;
        int s = g * 16 + ww * 8 + m;
        cmbB[ww][t * 8 + m] =
            (unsigned char)(num1[s * 128 + t] * 10 + num2[s * 128 + t]);
    }

    // ---- B-fragments from global (L2-cached, startup only) ----
    half8 Wf[4][2], Wdf[4];
    #pragma unroll
    for (int kt = 0; kt < 4; ++kt)
        #pragma unroll
        for (int j = 0; j < 8; ++j) {
            int k = kt * 16 + h32 * 8 + j;
            Wf[kt][0][j] = (_Float16)Whh[k * 64 + l5];
            Wf[kt][1][j] = (_Float16)Whh[k * 64 + 32 + l5];
            Wdf[kt][j]   = (l5 < 10) ? (_Float16)Wd[k * 10 + l5] : (_Float16)0.f;
        }
    float bdv = (l5 < 10) ? bd[l5] : 0.f;
    __syncthreads();   // last barrier

    const floatx16 z16 = {0.f,0.f,0.f,0.f,0.f,0.f,0.f,0.f,
                          0.f,0.f,0.f,0.f,0.f,0.f,0.f,0.f};
    const int orow = (s0 + 4 * h32) * 128;   // + r*128 later

    for (int t = 0; t < 128; ++t) {
        // PP prefetch (independent of h)
        int cw = ((const int*)cmbB[w])[t * 2 + h32];
        float pp[2][4];
        #pragma unroll
        for (int nt = 0; nt < 2; ++nt)
            #pragma unroll
            for (int r = 0; r < 4; ++r) {
                int cv = (cw >> (8 * r)) & 0xFF;
                pp[nt][r] = PPT[(nt * 32 + l5) * 101 + cv];
            }

        // A-fragments of h(t-1)
        half8 Ak[4];
        if (l5 < 8) {
            #pragma unroll
            for (int kt = 0; kt < 4; ++kt)
                Ak[kt] = *(const half8*)&Hh[w][l5][kt * 16 + h32 * 8];
        }

        // ---- recurrence: 4 independent MFMAs per N-half ----
        #pragma unroll
        for (int nt = 0; nt < 2; ++nt) {
            floatx16 C0 = MFMA32(Ak[0], Wf[0][nt], z16);
            floatx16 C1 = MFMA32(Ak[1], Wf[1][nt], z16);
            floatx16 C2 = MFMA32(Ak[2], Wf[2][nt], z16);
            floatx16 C3 = MFMA32(Ak[3], Wf[3][nt], z16);
            #pragma unroll
            for (int r = 0; r < 4; ++r) {
                float x  = ((C0[r] + C1[r]) + (C2[r] + C3[r])) + pp[nt][r];
                float e2 = __builtin_amdgcn_exp2f(x * 2.885390081777927f);
                float hv = 1.f - 2.f * __builtin_amdgcn_rcpf(e2 + 1.f);
                Hh[w][r + 4 * h32][nt * 32 + l5] = (_Float16)hv;
            }
        }

        // ---- projection of h(t-1) -> out[t-1], reusing Ak (off-path) ----
        if (t) {
            floatx16 Pa = MFMA32(Ak[0], Wdf[0], z16);
            Pa          = MFMA32(Ak[1], Wdf[1], Pa);
            floatx16 Pb = MFMA32(Ak[2], Wdf[2], z16);
            Pb          = MFMA32(Ak[3], Wdf[3], Pb);
            if (l5 < 10) {
                #pragma unroll
                for (int r = 0; r < 4; ++r)
                    out[(orow + r * 128 + (t - 1)) * 10 + l5] =
                        (Pa[r] + Pb[r]) + bdv;
            }
        }
    }

    // ---- final projection: h(127) -> out[127] ----
    half8 Fk[4];
    if (l5 < 8) {
        #pragma unroll
        for (int kt = 0; kt < 4; ++kt)
            Fk[kt] = *(const half8*)&Hh[w][l5][kt * 16 + h32 * 8];
    }
    floatx16 Pa = MFMA32(Fk[0], Wdf[0], z16);
    Pa          = MFMA32(Fk[1], Wdf[1], Pa);
    floatx16 Pb = MFMA32(Fk[2], Wdf[2], z16);
    Pb          = MFMA32(Fk[3], Wdf[3], Pb);
    if (l5 < 10) {
        #pragma unroll
        for (int r = 0; r < 4; ++r)
            out[(orow + r * 128 + 127) * 10 + l5] = (Pa[r] + Pb[r]) + bdv;
    }
}

extern "C" void kernel_launch(void* const* d_in, const int* in_sizes, int n_in,
                              void* d_out, int out_size, void* d_ws, size_t ws_size,
                              hipStream_t stream) {
    const int*   num1 = (const int*)d_in[0];
    const int*   num2 = (const int*)d_in[1];
    const float* E    = (const float*)d_in[2];
    const float* Wxh  = (const float*)d_in[3];
    const float* Whh  = (const float*)d_in[4];
    const float* b    = (const float*)d_in[5];
    const float* Wd   = (const float*)d_in[6];
    const float* bd   = (const float*)d_in[7];
    float* out = (float*)d_out;
    rnn_mfma7<<<256, 128, 0, stream>>>(num1, num2, E, Wxh, Whh, b, Wd, bd, out);
}